// Round 3
// baseline (3104.918 us; speedup 1.0000x reference)
//
#include <hip/hip_runtime.h>

#define NSEQ 6400
#define TMAX 20
#define EMB 300
#define EMBP 320
#define HID 512
#define KL0 832   // EMBP + HID
#define KL1 1024  // HID + HID
#define NQT 84
#define NANS 30000
#define RELN (NQT * NANS)

typedef __bf16 bf16x8 __attribute__((ext_vector_type(8)));
typedef float f32x4 __attribute__((ext_vector_type(4)));
typedef unsigned short u16;

__device__ __forceinline__ u16 f2bf(float f) {
  union { float f; unsigned int i; } v; v.f = f;
  unsigned int r = v.i + 0x7fffu + ((v.i >> 16) & 1u);
  return (u16)(r >> 16);
}

// ---------- embeddings: embT[t][n][EMBP] bf16, zero-padded cols [300,320) ----------
__global__ __launch_bounds__(320) void embed_kernel(
    const int* __restrict__ opt, const float* __restrict__ Wemb, u16* __restrict__ embT) {
  int bid = blockIdx.x;              // bid = t*NSEQ + n
  int n = bid % NSEQ, t = bid / NSEQ;
  int tok = opt[n * TMAX + t];
  int e = threadIdx.x;
  float v = 0.f;
  if (e < EMB && tok != 0) v = Wemb[(size_t)tok * EMB + e];
  embT[(size_t)bid * EMBP + e] = f2bf(v);
}

// ---------- weight repack to bf16, concatenated [ih | hh] along K ----------
__global__ void prep_w0(const float* __restrict__ wih, const float* __restrict__ whh,
                        u16* __restrict__ W) {
  for (int idx = blockIdx.x * blockDim.x + threadIdx.x; idx < 2048 * KL0;
       idx += gridDim.x * blockDim.x) {
    int o = idx / KL0, c = idx % KL0;
    float v;
    if (c < EMB) v = wih[o * EMB + c];
    else if (c < EMBP) v = 0.f;
    else v = whh[o * HID + (c - EMBP)];
    W[idx] = f2bf(v);
  }
}
__global__ void prep_w1(const float* __restrict__ wih, const float* __restrict__ whh,
                        u16* __restrict__ W) {
  for (int idx = blockIdx.x * blockDim.x + threadIdx.x; idx < 2048 * KL1;
       idx += gridDim.x * blockDim.x) {
    int o = idx / KL1, c = idx % KL1;
    float v = (c < HID) ? wih[o * HID + c] : whh[o * HID + (c - HID)];
    W[idx] = f2bf(v);
  }
}
__global__ void prep_bias(const float* __restrict__ a, const float* __restrict__ b,
                          float* __restrict__ o) {
  int i = blockIdx.x * blockDim.x + threadIdx.x;
  if (i < 2048) o[i] = a[i] + b[i];
}

// ---------- fused GEMM + LSTM cell step ----------
// Tile: 128 rows x 32 hidden x 4 gates (effective 128x128). 4 waves (2x2).
// A = [segA0 | segA1] along K (bf16, row-major). B = Wcat [2048][Ktot] bf16 (B^T form).
// Epilogue: each wave holds all 4 gates for its (row,hidden) elements in-register.
__global__ __launch_bounds__(256) void lstm_step(
    const u16* __restrict__ segA0, int strideA0, int K0,
    const u16* __restrict__ segA1,                 // stride HID; also h_old (bf16)
    const u16* __restrict__ Wcat, int Ktot, int nK,
    const float* __restrict__ biasc,
    u16* __restrict__ h_new, float* __restrict__ c_state,
    const float* __restrict__ hf_old, float* __restrict__ hf_new,  // f32 h (layer1 only)
    const int* __restrict__ lens, int t) {
  __shared__ __align__(16) u16 Atile[128 * 32];    // 8 KB
  __shared__ __align__(16) u16 Btile[128 * 32];    // 8 KB (4 gates x 32 hidden rows)
  const int tid = threadIdx.x;
  const int wave = tid >> 6, lane = tid & 63;
  const int l15 = lane & 15, l4 = lane >> 4;
  const int wr = wave >> 1, wc = wave & 1;
  const int rowBlk = blockIdx.y * 128;
  const int hb = blockIdx.x * 32;

  f32x4 acc[4][4] = {};   // [row-frag][gate]

  // staging: 8 x 1KB global_load_lds for A (waves 0-1), 8 for B (waves 2-3)
  const bool isA = wave < 2;
  const int ld0 = (wave & 1) * 4;
  const int jhi = lane >> 2;         // row-within-load (0..15)
  const int slot = (lane & 3) * 8;   // k element offset within 64B row-chunk
  int off0[4], off1[4];
#pragma unroll
  for (int i = 0; i < 4; ++i) {
    int r = (ld0 + i) * 16 + jhi;    // 0..127
    if (isA) {
      off0[i] = (rowBlk + r) * strideA0 + slot;
      off1[i] = (rowBlk + r) * HID + slot;
    } else {
      int g = r >> 5, h = r & 31;
      off0[i] = (g * HID + hb + h) * Ktot + slot;
      off1[i] = 0;
    }
  }

  for (int ks = 0; ks < nK; ++ks) {
    const int kbase = ks * 32;
    if (isA) {
      const bool s1 = kbase >= K0;
      const u16* base = s1 ? (segA1 + (kbase - K0)) : (segA0 + kbase);
#pragma unroll
      for (int i = 0; i < 4; ++i) {
        const u16* gp = base + (s1 ? off1[i] : off0[i]);
        __builtin_amdgcn_global_load_lds(
            (__attribute__((address_space(1))) void*)gp,
            (__attribute__((address_space(3))) void*)(Atile + (ld0 + i) * 512),
            16, 0, 0);
      }
    } else {
#pragma unroll
      for (int i = 0; i < 4; ++i) {
        const u16* gp = Wcat + off0[i] + kbase;
        __builtin_amdgcn_global_load_lds(
            (__attribute__((address_space(1))) void*)gp,
            (__attribute__((address_space(3))) void*)(Btile + (ld0 + i) * 512),
            16, 0, 0);
      }
    }
    __syncthreads();   // drains vmcnt(0) then barrier: staged tiles visible

    bf16x8 a[4], b[4];
#pragma unroll
    for (int m = 0; m < 4; ++m)
      a[m] = *(const bf16x8*)(Atile + (wr * 64 + m * 16 + l15) * 32 + l4 * 8);
#pragma unroll
    for (int g = 0; g < 4; ++g)
      b[g] = *(const bf16x8*)(Btile + (g * 32 + wc * 16 + l15) * 32 + l4 * 8);
#pragma unroll
    for (int m = 0; m < 4; ++m)
#pragma unroll
      for (int g = 0; g < 4; ++g)
        acc[m][g] = __builtin_amdgcn_mfma_f32_16x16x32_bf16(a[m], b[g], acc[m][g], 0, 0, 0);
    __syncthreads();   // LDS reuse barrier
  }

  // epilogue: LSTM cell update. C/D frag: col = lane&15, row = (lane>>4)*4 + reg
  const int u = hb + wc * 16 + l15;
  const float bi = biasc[u], bf = biasc[512 + u], bg = biasc[1024 + u], bo = biasc[1536 + u];
#pragma unroll
  for (int m = 0; m < 4; ++m) {
    const int rbase = rowBlk + wr * 64 + m * 16 + l4 * 4;
#pragma unroll
    for (int jj = 0; jj < 4; ++jj) {
      const int r = rbase + jj;
      const size_t idx = (size_t)r * HID + u;
      float ip = acc[m][0][jj] + bi;
      float fp = acc[m][1][jj] + bf;
      float gp = acc[m][2][jj] + bg;
      float op = acc[m][3][jj] + bo;
      float co = c_state[idx];
      float si = 1.f / (1.f + __expf(-ip));
      float sf = 1.f / (1.f + __expf(-fp));
      float so = 1.f / (1.f + __expf(-op));
      float tg = tanhf(gp);
      float cn = sf * co + si * tg;
      float hn = so * tanhf(cn);
      bool act = t < lens[r];
      c_state[idx] = act ? cn : co;
      h_new[idx] = act ? f2bf(hn) : segA1[idx];
      if (hf_new) hf_new[idx] = act ? hn : hf_old[idx];
    }
  }
}

// ---------- scores: out[n] = dot(h2[n,:], enc[n/100,:]) ----------
__global__ __launch_bounds__(256) void scores_kernel(
    const float* __restrict__ h2, const float* __restrict__ enc, float* __restrict__ out) {
  int n = blockIdx.x * 4 + (threadIdx.x >> 6);
  int lane = threadIdx.x & 63;
  const float4* hp = (const float4*)(h2 + (size_t)n * HID + lane * 8);
  const float4* ep = (const float4*)(enc + (size_t)(n / 100) * HID + lane * 8);
  float4 h0 = hp[0], h1 = hp[1], e0 = ep[0], e1 = ep[1];
  float s = h0.x * e0.x + h0.y * e0.y + h0.z * e0.z + h0.w * e0.w +
            h1.x * e1.x + h1.y * e1.y + h1.z * e1.z + h1.w * e1.w;
#pragma unroll
  for (int off = 32; off; off >>= 1) s += __shfl_xor(s, off);
  if (lane == 0) out[n] = s;
}

// ---------- relevance dtype detection (bool may arrive as u8/i32/i64/f32) ----------
// Scan only the minimum possible buffer size (RELN bytes) -- safe for all layouts.
__global__ void detect_kernel(const unsigned char* __restrict__ rel, int* __restrict__ flags) {
  int a = 0, bb = 0, z = 0;
  for (int i = blockIdx.x * blockDim.x + threadIdx.x; i < RELN; i += gridDim.x * blockDim.x) {
    if (rel[i]) {
      if (i & 3) a = 1; else z = 1;
      if (i & 4) bb = 1;
    }
  }
  if (a) atomicOr(&flags[0], 1);
  if (bb) atomicOr(&flags[1], 1);
  if (z) atomicOr(&flags[2], 1);
}

__global__ void qt_kernel(const void* __restrict__ rel, const int* __restrict__ qt_idx,
                          const int* __restrict__ opt_idx, const int* __restrict__ flags,
                          float* __restrict__ out) {
  int n = blockIdx.x * blockDim.x + threadIdx.x;
  if (n >= NSEQ) return;
  long long idx = (long long)qt_idx[n / 100] * NANS + opt_idx[n];
  int fa = flags[0], fb = flags[1], fz = flags[2];
  bool hit;
  if (fa && fz)       hit = ((const unsigned char*)rel)[idx] != 0;   // uint8 bool
  else if (fa)        hit = ((const float*)rel)[idx] != 0.f;         // float32
  else if (fb)        hit = ((const int*)rel)[idx] != 0;             // int32
  else                hit = ((const long long*)rel)[idx] != 0;       // int64
  out[NSEQ + n] = hit ? 1.f : 0.f;
}

extern "C" void kernel_launch(void* const* d_in, const int* in_sizes, int n_in,
                              void* d_out, int out_size, void* d_ws, size_t ws_size,
                              hipStream_t stream) {
  (void)in_sizes; (void)n_in; (void)out_size; (void)ws_size;
  const float* enc    = (const float*)d_in[0];
  const int*   opt    = (const int*)d_in[1];
  const int*   optlen = (const int*)d_in[2];
  const int*   qtidx  = (const int*)d_in[3];
  const int*   optidx = (const int*)d_in[4];
  const float* Wemb   = (const float*)d_in[5];
  const float* wih0   = (const float*)d_in[6];
  const float* whh0   = (const float*)d_in[7];
  const float* bih0   = (const float*)d_in[8];
  const float* bhh0   = (const float*)d_in[9];
  const float* wih1   = (const float*)d_in[10];
  const float* whh1   = (const float*)d_in[11];
  const float* bih1   = (const float*)d_in[12];
  const float* bhh1   = (const float*)d_in[13];
  const void*  rel    = d_in[14];
  float* out = (float*)d_out;

  char* ws = (char*)d_ws;
  size_t off = 0;
  auto alloc = [&](size_t bytes) -> void* {
    void* p = (void*)(ws + off);
    off += (bytes + 255) & ~(size_t)255;
    return p;
  };
  // total ~168 MB of workspace
  u16* embT   = (u16*)alloc((size_t)TMAX * NSEQ * EMBP * 2);
  u16* W0     = (u16*)alloc((size_t)2048 * KL0 * 2);
  u16* W1     = (u16*)alloc((size_t)2048 * KL1 * 2);
  float* bc0  = (float*)alloc(2048 * 4);
  float* bc1  = (float*)alloc(2048 * 4);
  u16* h0b[2] = { (u16*)alloc((size_t)NSEQ * HID * 2), (u16*)alloc((size_t)NSEQ * HID * 2) };
  u16* h1b[2] = { (u16*)alloc((size_t)NSEQ * HID * 2), (u16*)alloc((size_t)NSEQ * HID * 2) };
  float* c0   = (float*)alloc((size_t)NSEQ * HID * 4);
  float* c1   = (float*)alloc((size_t)NSEQ * HID * 4);
  float* hf[2] = { (float*)alloc((size_t)NSEQ * HID * 4), (float*)alloc((size_t)NSEQ * HID * 4) };
  int* flags  = (int*)alloc(16);

  hipMemsetAsync(h0b[0], 0, (size_t)NSEQ * HID * 2, stream);
  hipMemsetAsync(h1b[0], 0, (size_t)NSEQ * HID * 2, stream);
  hipMemsetAsync(c0, 0, (size_t)NSEQ * HID * 4, stream);
  hipMemsetAsync(c1, 0, (size_t)NSEQ * HID * 4, stream);
  hipMemsetAsync(hf[0], 0, (size_t)NSEQ * HID * 4, stream);
  hipMemsetAsync(flags, 0, 16, stream);

  embed_kernel<<<TMAX * NSEQ, EMBP, 0, stream>>>(opt, Wemb, embT);
  prep_w0<<<512, 256, 0, stream>>>(wih0, whh0, W0);
  prep_w1<<<512, 256, 0, stream>>>(wih1, whh1, W1);
  prep_bias<<<8, 256, 0, stream>>>(bih0, bhh0, bc0);
  prep_bias<<<8, 256, 0, stream>>>(bih1, bhh1, bc1);
  detect_kernel<<<256, 256, 0, stream>>>((const unsigned char*)rel, flags);

  dim3 grid(16, 50), blk(256);
  for (int t = 0; t < TMAX; ++t) {
    int cur = t & 1, nxt = cur ^ 1;
    // layer 0: A = [emb_t | h0], B = W0cat
    lstm_step<<<grid, blk, 0, stream>>>(
        embT + (size_t)t * NSEQ * EMBP, EMBP, EMBP,
        h0b[cur], W0, KL0, KL0 / 32, bc0,
        h0b[nxt], c0, nullptr, nullptr, optlen, t);
    // layer 1: A = [h0_new | h1], B = W1cat
    lstm_step<<<grid, blk, 0, stream>>>(
        h0b[nxt], HID, HID,
        h1b[cur], W1, KL1, KL1 / 32, bc1,
        h1b[nxt], c1, hf[cur], hf[nxt], optlen, t);
  }

  scores_kernel<<<NSEQ / 4, 256, 0, stream>>>(hf[0], enc, out);
  qt_kernel<<<(NSEQ + 255) / 256, 256, 0, stream>>>(rel, qtidx, optidx, flags, out);
}

// Round 4
// 2458.880 us; speedup vs baseline: 1.2627x; 1.2627x over previous
//
#include <hip/hip_runtime.h>

#define NSEQ 6400
#define TMAX 20
#define EMB 300
#define EMBP 320
#define HID 512
#define KL0 832   // EMBP + HID
#define KL1 1024  // HID + HID
#define NQT 84
#define NANS 30000
#define RELN (NQT * NANS)

typedef __bf16 bf16x8 __attribute__((ext_vector_type(8)));
typedef float f32x4 __attribute__((ext_vector_type(4)));
typedef unsigned short u16;

__device__ __forceinline__ u16 f2bf(float f) {
  union { float f; unsigned int i; } v; v.f = f;
  unsigned int r = v.i + 0x7fffu + ((v.i >> 16) & 1u);
  return (u16)(r >> 16);
}

// ---------- embeddings: embT[t][n][EMBP] bf16, zero-padded cols [300,320) ----------
__global__ __launch_bounds__(320) void embed_kernel(
    const int* __restrict__ opt, const float* __restrict__ Wemb, u16* __restrict__ embT) {
  int n = blockIdx.x;
  int e = threadIdx.x;
#pragma unroll 4
  for (int t = 0; t < TMAX; ++t) {
    int tok = opt[n * TMAX + t];
    float v = 0.f;
    if (e < EMB && tok != 0) v = Wemb[(size_t)tok * EMB + e];
    embT[((size_t)t * NSEQ + n) * EMBP + e] = f2bf(v);
  }
}

// ---------- weight repack to bf16, concatenated [ih | hh] along K ----------
__global__ void prep_w0(const float* __restrict__ wih, const float* __restrict__ whh,
                        u16* __restrict__ W) {
  for (int idx = blockIdx.x * blockDim.x + threadIdx.x; idx < 2048 * KL0;
       idx += gridDim.x * blockDim.x) {
    int o = idx / KL0, c = idx % KL0;
    float v;
    if (c < EMB) v = wih[o * EMB + c];
    else if (c < EMBP) v = 0.f;
    else v = whh[o * HID + (c - EMBP)];
    W[idx] = f2bf(v);
  }
}
__global__ void prep_w1(const float* __restrict__ wih, const float* __restrict__ whh,
                        u16* __restrict__ W) {
  for (int idx = blockIdx.x * blockDim.x + threadIdx.x; idx < 2048 * KL1;
       idx += gridDim.x * blockDim.x) {
    int o = idx / KL1, c = idx % KL1;
    float v = (c < HID) ? wih[o * HID + c] : whh[o * HID + (c - HID)];
    W[idx] = f2bf(v);
  }
}
__global__ void prep_bias(const float* __restrict__ a, const float* __restrict__ b,
                          float* __restrict__ o) {
  int i = blockIdx.x * blockDim.x + threadIdx.x;
  if (i < 2048) o[i] = a[i] + b[i];
}

// ---------- fused GEMM + LSTM cell step (2-phase dbuf + swizzle + XCD remap) ------
// Tile: 128 rows x 32 hidden x 4 gates. 4 waves (2x2). LDS double-buffered.
// LDS XOR swizzle: content[row][slot] = global[row][slot ^ ((row>>1)&3)]
//   (pre-swizzled SOURCE with linear global_load_lds dest; reader applies same XOR)
// c_state / hf are COLUMN-major [HID][NSEQ] for float4 epilogue access.
__global__ __launch_bounds__(256) void lstm_step(
    const u16* __restrict__ segA0, int strideA0, int K0,
    const u16* __restrict__ segA1,                 // [NSEQ][HID] bf16, h_old
    const u16* __restrict__ Wcat, int Ktot, int nK,
    const float* __restrict__ biasc,
    u16* __restrict__ h_new, float* __restrict__ c_state,
    const float* __restrict__ hf_old, float* __restrict__ hf_new,
    const int* __restrict__ lens, int t) {
  __shared__ __align__(16) u16 Atile[2][128 * 32];   // 8 KB x2
  __shared__ __align__(16) u16 Btile[2][128 * 32];
  const int tid = threadIdx.x;
  const int wave = tid >> 6, lane = tid & 63;
  const int l15 = lane & 15, l4 = lane >> 4;
  const int wr = wave >> 1, wc = wave & 1;

  // XCD-aware remap: 800 blocks, 8 XCDs -> chunk of 100 consecutive nids per XCD.
  // Consecutive nids share blockIdx-y (A row strip) -> A stays in one XCD's L2.
  const int orig = blockIdx.x;
  const int nid = (orig & 7) * 100 + (orig >> 3);
  const int rowBlk = (nid >> 4) * 128;
  const int hb = (nid & 15) * 32;

  const bool isA = wave < 2;
  const int ld0 = (wave & 1) * 4;
  int offg[4], offg1[4];
#pragma unroll
  for (int i = 0; i < 4; ++i) {
    int lrow = (ld0 + i) * 16 + (lane >> 2);           // 0..127 tile row
    int srcslot = (lane & 3) ^ ((lrow >> 1) & 3);      // pre-swizzled 16B slot
    if (isA) {
      offg[i]  = (rowBlk + lrow) * strideA0 + srcslot * 8;
      offg1[i] = (rowBlk + lrow) * HID + srcslot * 8;
    } else {
      int g = lrow >> 5, h = lrow & 31;
      offg[i]  = (g * HID + hb + h) * Ktot + srcslot * 8;
      offg1[i] = 0;
    }
  }

  auto stage = [&](int sel, int ks) {
    const int kbase = ks * 32;
    if (isA) {
      const bool s1 = kbase >= K0;
      const u16* base = s1 ? (segA1 + (kbase - K0)) : (segA0 + kbase);
      const int* off = s1 ? offg1 : offg;
#pragma unroll
      for (int i = 0; i < 4; ++i)
        __builtin_amdgcn_global_load_lds(
            (const __attribute__((address_space(1))) void*)(base + off[i]),
            (__attribute__((address_space(3))) void*)(&Atile[sel][(ld0 + i) * 512]),
            16, 0, 0);
    } else {
#pragma unroll
      for (int i = 0; i < 4; ++i)
        __builtin_amdgcn_global_load_lds(
            (const __attribute__((address_space(1))) void*)(Wcat + offg[i] + kbase),
            (__attribute__((address_space(3))) void*)(&Btile[sel][(ld0 + i) * 512]),
            16, 0, 0);
    }
  };

  f32x4 acc[4][4] = {};
  const int kx = (l4 ^ ((l15 >> 1) & 3)) * 8;   // swizzled read offset (elements)

  auto compute = [&](int sel) {
    bf16x8 a[4], b[4];
#pragma unroll
    for (int m = 0; m < 4; ++m)
      a[m] = *(const bf16x8*)(&Atile[sel][(wr * 64 + m * 16 + l15) * 32 + kx]);
#pragma unroll
    for (int g = 0; g < 4; ++g)
      b[g] = *(const bf16x8*)(&Btile[sel][(g * 32 + wc * 16 + l15) * 32 + kx]);
#pragma unroll
    for (int m = 0; m < 4; ++m)
#pragma unroll
      for (int g = 0; g < 4; ++g)
        acc[m][g] = __builtin_amdgcn_mfma_f32_16x16x32_bf16(a[m], b[g], acc[m][g], 0, 0, 0);
  };

  // 2-phase pipeline: stage(t+1) issued BEFORE compute(t); single barrier per step.
  stage(0, 0);
  __syncthreads();
  int cur = 0;
  for (int ks = 0; ks < nK - 1; ++ks) {
    stage(cur ^ 1, ks + 1);
    compute(cur);
    __syncthreads();
    cur ^= 1;
  }
  compute(cur);

  // epilogue: LSTM cell. C/D frag: col = lane&15, row = (lane>>4)*4 + reg
  const int u = hb + wc * 16 + l15;
  const float bi = biasc[u], bff = biasc[512 + u], bg = biasc[1024 + u], bo = biasc[1536 + u];
#pragma unroll
  for (int m = 0; m < 4; ++m) {
    const int rbase = rowBlk + wr * 64 + m * 16 + l4 * 4;
    const size_t cmi = (size_t)u * NSEQ + rbase;       // column-major index
    f32x4 co4 = *(const f32x4*)(c_state + cmi);
    int4 ln4 = *(const int4*)(lens + rbase);
    f32x4 ho4;
    if (hf_new) ho4 = *(const f32x4*)(hf_old + cmi);
    f32x4 cn4, hn4;
    u16 hstore[4];
#pragma unroll
    for (int jj = 0; jj < 4; ++jj) {
      const int r = rbase + jj;
      float ip = acc[m][0][jj] + bi;
      float fp = acc[m][1][jj] + bff;
      float gp = acc[m][2][jj] + bg;
      float op = acc[m][3][jj] + bo;
      float co = co4[jj];
      float si = 1.f / (1.f + __expf(-ip));
      float sf = 1.f / (1.f + __expf(-fp));
      float so = 1.f / (1.f + __expf(-op));
      float tg = tanhf(gp);
      float cn = sf * co + si * tg;
      float hn = so * tanhf(cn);
      int len = (jj == 0) ? ln4.x : (jj == 1) ? ln4.y : (jj == 2) ? ln4.z : ln4.w;
      bool act = t < len;
      cn4[jj] = act ? cn : co;
      hstore[jj] = act ? f2bf(hn) : segA1[(size_t)r * HID + u];
      if (hf_new) hn4[jj] = act ? hn : ho4[jj];
    }
    *(f32x4*)(c_state + cmi) = cn4;
    if (hf_new) *(f32x4*)(hf_new + cmi) = hn4;
#pragma unroll
    for (int jj = 0; jj < 4; ++jj)
      h_new[(size_t)(rbase + jj) * HID + u] = hstore[jj];
  }
}

// ---------- scores: out[n] = dot(h2[:,n] (col-major), enc[n/100,:]) ----------
__global__ __launch_bounds__(256) void scores_kernel(
    const float* __restrict__ h2cm, const float* __restrict__ enc, float* __restrict__ out) {
  int n = (blockIdx.x >> 1) * 256 + threadIdx.x;      // 25 n-blocks x 2 u-halves
  int uh = (blockIdx.x & 1) * 256;
  const float* ep = enc + (n / 100) * HID + uh;
  float s = 0.f;
#pragma unroll 8
  for (int u = 0; u < 256; ++u) s += h2cm[(size_t)(uh + u) * NSEQ + n] * ep[u];
  atomicAdd(&out[n], s);
}

// ---------- relevance dtype detection (bool may arrive as u8/i32/i64/f32) ----------
__global__ void detect_kernel(const unsigned char* __restrict__ rel, int* __restrict__ flags) {
  int a = 0, bb = 0, z = 0;
  for (int i = blockIdx.x * blockDim.x + threadIdx.x; i < RELN; i += gridDim.x * blockDim.x) {
    if (rel[i]) {
      if (i & 3) a = 1; else z = 1;
      if (i & 4) bb = 1;
    }
  }
  if (a) atomicOr(&flags[0], 1);
  if (bb) atomicOr(&flags[1], 1);
  if (z) atomicOr(&flags[2], 1);
}

__global__ void qt_kernel(const void* __restrict__ rel, const int* __restrict__ qt_idx,
                          const int* __restrict__ opt_idx, const int* __restrict__ flags,
                          float* __restrict__ out) {
  int n = blockIdx.x * blockDim.x + threadIdx.x;
  if (n >= NSEQ) return;
  long long idx = (long long)qt_idx[n / 100] * NANS + opt_idx[n];
  int fa = flags[0], fb = flags[1], fz = flags[2];
  bool hit;
  if (fa && fz)       hit = ((const unsigned char*)rel)[idx] != 0;   // uint8 bool
  else if (fa)        hit = ((const float*)rel)[idx] != 0.f;         // float32
  else if (fb)        hit = ((const int*)rel)[idx] != 0;             // int32
  else                hit = ((const long long*)rel)[idx] != 0;       // int64
  out[NSEQ + n] = hit ? 1.f : 0.f;
}

extern "C" void kernel_launch(void* const* d_in, const int* in_sizes, int n_in,
                              void* d_out, int out_size, void* d_ws, size_t ws_size,
                              hipStream_t stream) {
  (void)in_sizes; (void)n_in; (void)out_size; (void)ws_size;
  const float* enc    = (const float*)d_in[0];
  const int*   opt    = (const int*)d_in[1];
  const int*   optlen = (const int*)d_in[2];
  const int*   qtidx  = (const int*)d_in[3];
  const int*   optidx = (const int*)d_in[4];
  const float* Wemb   = (const float*)d_in[5];
  const float* wih0   = (const float*)d_in[6];
  const float* whh0   = (const float*)d_in[7];
  const float* bih0   = (const float*)d_in[8];
  const float* bhh0   = (const float*)d_in[9];
  const float* wih1   = (const float*)d_in[10];
  const float* whh1   = (const float*)d_in[11];
  const float* bih1   = (const float*)d_in[12];
  const float* bhh1   = (const float*)d_in[13];
  const void*  rel    = d_in[14];
  float* out = (float*)d_out;

  char* ws = (char*)d_ws;
  size_t off = 0;
  auto alloc = [&](size_t bytes) -> void* {
    void* p = (void*)(ws + off);
    off += (bytes + 255) & ~(size_t)255;
    return p;
  };
  u16* embT   = (u16*)alloc((size_t)TMAX * NSEQ * EMBP * 2);
  u16* W0     = (u16*)alloc((size_t)2048 * KL0 * 2);
  u16* W1     = (u16*)alloc((size_t)2048 * KL1 * 2);
  float* bc0  = (float*)alloc(2048 * 4);
  float* bc1  = (float*)alloc(2048 * 4);
  u16* h0b[2] = { (u16*)alloc((size_t)NSEQ * HID * 2), (u16*)alloc((size_t)NSEQ * HID * 2) };
  u16* h1b[2] = { (u16*)alloc((size_t)NSEQ * HID * 2), (u16*)alloc((size_t)NSEQ * HID * 2) };
  float* c0   = (float*)alloc((size_t)NSEQ * HID * 4);
  float* c1   = (float*)alloc((size_t)NSEQ * HID * 4);
  float* hf[2] = { (float*)alloc((size_t)NSEQ * HID * 4), (float*)alloc((size_t)NSEQ * HID * 4) };
  int* flags  = (int*)alloc(16);

  hipMemsetAsync(h0b[0], 0, (size_t)NSEQ * HID * 2, stream);
  hipMemsetAsync(h1b[0], 0, (size_t)NSEQ * HID * 2, stream);
  hipMemsetAsync(c0, 0, (size_t)NSEQ * HID * 4, stream);
  hipMemsetAsync(c1, 0, (size_t)NSEQ * HID * 4, stream);
  hipMemsetAsync(hf[0], 0, (size_t)NSEQ * HID * 4, stream);
  hipMemsetAsync(flags, 0, 16, stream);
  hipMemsetAsync(out, 0, (size_t)NSEQ * 4, stream);   // scores accumulated atomically

  embed_kernel<<<NSEQ, EMBP, 0, stream>>>(opt, Wemb, embT);
  prep_w0<<<512, 256, 0, stream>>>(wih0, whh0, W0);
  prep_w1<<<512, 256, 0, stream>>>(wih1, whh1, W1);
  prep_bias<<<8, 256, 0, stream>>>(bih0, bhh0, bc0);
  prep_bias<<<8, 256, 0, stream>>>(bih1, bhh1, bc1);
  detect_kernel<<<256, 256, 0, stream>>>((const unsigned char*)rel, flags);

  for (int t = 0; t < TMAX; ++t) {
    int cur = t & 1, nxt = cur ^ 1;
    // layer 0: A = [emb_t | h0], B = W0cat
    lstm_step<<<800, 256, 0, stream>>>(
        embT + (size_t)t * NSEQ * EMBP, EMBP, EMBP,
        h0b[cur], W0, KL0, KL0 / 32, bc0,
        h0b[nxt], c0, nullptr, nullptr, optlen, t);
    // layer 1: A = [h0_new | h1], B = W1cat
    lstm_step<<<800, 256, 0, stream>>>(
        h0b[nxt], HID, HID,
        h1b[cur], W1, KL1, KL1 / 32, bc1,
        h1b[nxt], c1, hf[cur], hf[nxt], optlen, t);
  }

  scores_kernel<<<50, 256, 0, stream>>>(hf[0], enc, out);
  qt_kernel<<<(NSEQ + 255) / 256, 256, 0, stream>>>(rel, qtidx, optidx, flags, out);
}

// Round 9
// 2227.889 us; speedup vs baseline: 1.3937x; 1.1037x over previous
//
#include <hip/hip_runtime.h>

#define NSEQ 6400
#define TMAX 20
#define EMB 300
#define EMBP 320
#define HID 512
#define KL0 832   // EMBP + HID
#define KL1 1024  // HID + HID
#define NQT 84
#define NANS 30000
#define RELN (NQT * NANS)

typedef __bf16 bf16x8 __attribute__((ext_vector_type(8)));
typedef float f32x4 __attribute__((ext_vector_type(4)));
typedef unsigned short u16;

__device__ __forceinline__ u16 f2bf(float f) {
  union { float f; unsigned int i; } v; v.f = f;
  unsigned int r = v.i + 0x7fffu + ((v.i >> 16) & 1u);
  return (u16)(r >> 16);
}

// ---------- embeddings: embT[t][n][EMBP] bf16, zero-padded cols [300,320) ----------
__global__ __launch_bounds__(320) void embed_kernel(
    const int* __restrict__ opt, const float* __restrict__ Wemb, u16* __restrict__ embT) {
  int n = blockIdx.x;
  int e = threadIdx.x;
#pragma unroll 4
  for (int t = 0; t < TMAX; ++t) {
    int tok = opt[n * TMAX + t];
    float v = 0.f;
    if (e < EMB && tok != 0) v = Wemb[(size_t)tok * EMB + e];
    embT[((size_t)t * NSEQ + n) * EMBP + e] = f2bf(v);
  }
}

// ---------- weight repack to bf16, concatenated [ih | hh] along K ----------
__global__ void prep_w0(const float* __restrict__ wih, const float* __restrict__ whh,
                        u16* __restrict__ W) {
  for (int idx = blockIdx.x * blockDim.x + threadIdx.x; idx < 2048 * KL0;
       idx += gridDim.x * blockDim.x) {
    int o = idx / KL0, c = idx % KL0;
    float v;
    if (c < EMB) v = wih[o * EMB + c];
    else if (c < EMBP) v = 0.f;
    else v = whh[o * HID + (c - EMBP)];
    W[idx] = f2bf(v);
  }
}
__global__ void prep_w1(const float* __restrict__ wih, const float* __restrict__ whh,
                        u16* __restrict__ W) {
  for (int idx = blockIdx.x * blockDim.x + threadIdx.x; idx < 2048 * KL1;
       idx += gridDim.x * blockDim.x) {
    int o = idx / KL1, c = idx % KL1;
    float v = (c < HID) ? wih[o * HID + c] : whh[o * HID + (c - HID)];
    W[idx] = f2bf(v);
  }
}
__global__ void prep_bias(const float* __restrict__ a, const float* __restrict__ b,
                          float* __restrict__ o) {
  int i = blockIdx.x * blockDim.x + threadIdx.x;
  if (i < 2048) o[i] = a[i] + b[i];
}

// ---------- fused GEMM + LSTM cell step -------------------------------------------
// Tile: 128 rows x 32 hidden x 4 gates. 4 waves (2x2).
// 3-buffer, 2-ahead pipeline with COUNTED vmcnt (T3+T4): the 2 newest stages'
// loads (8/wave) stay in flight across barriers; we only wait for the oldest.
// LDS XOR swizzle (pre-swizzled source + swizzled read) keeps ds_read conflict-free.
// c_state / hf are COLUMN-major [HID][NSEQ] for float4 epilogue access.
__global__ __launch_bounds__(256) void lstm_step(
    const u16* __restrict__ segA0, int strideA0, int K0,
    const u16* __restrict__ segA1,                 // [NSEQ][HID] bf16, h_old
    const u16* __restrict__ Wcat, int Ktot, int nK,
    const float* __restrict__ biasc,
    u16* __restrict__ h_new, float* __restrict__ c_state,
    const float* __restrict__ hf_old, float* __restrict__ hf_new,
    const int* __restrict__ lens, int t) {
  __shared__ __align__(16) u16 Atile[3][128 * 32];   // 8 KB x3
  __shared__ __align__(16) u16 Btile[3][128 * 32];   // 8 KB x3  (48 KB total -> 3 blk/CU)
  const int tid = threadIdx.x;
  const int wave = tid >> 6, lane = tid & 63;
  const int l15 = lane & 15, l4 = lane >> 4;
  const int wr = wave >> 1, wc = wave & 1;

  // XCD-aware remap: 800 blocks, 8 XCDs -> chunk of 100 consecutive nids per XCD.
  const int orig = blockIdx.x;
  const int nid = (orig & 7) * 100 + (orig >> 3);
  const int rowBlk = (nid >> 4) * 128;
  const int hb = (nid & 15) * 32;

  const bool isA = wave < 2;
  const int ld0 = (wave & 1) * 4;
  int offg[4], offg1[4];
#pragma unroll
  for (int i = 0; i < 4; ++i) {
    int lrow = (ld0 + i) * 16 + (lane >> 2);           // 0..127 tile row
    int srcslot = (lane & 3) ^ ((lrow >> 1) & 3);      // pre-swizzled 16B slot
    if (isA) {
      offg[i]  = (rowBlk + lrow) * strideA0 + srcslot * 8;
      offg1[i] = (rowBlk + lrow) * HID + srcslot * 8;
    } else {
      int g = lrow >> 5, h = lrow & 31;
      offg[i]  = (g * HID + hb + h) * Ktot + srcslot * 8;
      offg1[i] = 0;
    }
  }

  auto stage = [&](int sel, int ks) {
    const int kbase = ks * 32;
    if (isA) {
      const bool s1 = kbase >= K0;
      const u16* base = s1 ? (segA1 + (kbase - K0)) : (segA0 + kbase);
      const int* off = s1 ? offg1 : offg;
#pragma unroll
      for (int i = 0; i < 4; ++i)
        __builtin_amdgcn_global_load_lds(
            (const __attribute__((address_space(1))) void*)(base + off[i]),
            (__attribute__((address_space(3))) void*)(&Atile[sel][(ld0 + i) * 512]),
            16, 0, 0);
    } else {
#pragma unroll
      for (int i = 0; i < 4; ++i)
        __builtin_amdgcn_global_load_lds(
            (const __attribute__((address_space(1))) void*)(Wcat + offg[i] + kbase),
            (__attribute__((address_space(3))) void*)(&Btile[sel][(ld0 + i) * 512]),
            16, 0, 0);
    }
  };

  f32x4 acc[4][4] = {};
  const int kx = (l4 ^ ((l15 >> 1) & 3)) * 8;   // swizzled read offset (elements)

  auto compute = [&](int sel) {
    bf16x8 a[4], b[4];
#pragma unroll
    for (int m = 0; m < 4; ++m)
      a[m] = *(const bf16x8*)(&Atile[sel][(wr * 64 + m * 16 + l15) * 32 + kx]);
#pragma unroll
    for (int g = 0; g < 4; ++g)
      b[g] = *(const bf16x8*)(&Btile[sel][(g * 32 + wc * 16 + l15) * 32 + kx]);
    __builtin_amdgcn_s_setprio(1);
#pragma unroll
    for (int m = 0; m < 4; ++m)
#pragma unroll
      for (int g = 0; g < 4; ++g)
        acc[m][g] = __builtin_amdgcn_mfma_f32_16x16x32_bf16(a[m], b[g], acc[m][g], 0, 0, 0);
    __builtin_amdgcn_s_setprio(0);
  };

  // Pipeline: 2-ahead prefetch, counted vmcnt (8 = two newest stages in flight).
  // Post-compute barrier protects b[ks%3] from stage(ks+3) in the next iteration.
  stage(0, 0);
  stage(1, 1);
  int sel = 0, pre = 2;
  for (int ks = 0; ks < nK; ++ks) {
    if (ks + 2 < nK) {
      stage(pre, ks + 2);
      if (++pre == 3) pre = 0;
      asm volatile("s_waitcnt vmcnt(8)" ::: "memory");
    } else if (ks + 1 < nK) {
      asm volatile("s_waitcnt vmcnt(4)" ::: "memory");
    } else {
      asm volatile("s_waitcnt vmcnt(0)" ::: "memory");
    }
    __builtin_amdgcn_s_barrier();
    compute(sel);
    if (++sel == 3) sel = 0;
    if (ks + 1 < nK) __builtin_amdgcn_s_barrier();
  }

  // epilogue: LSTM cell. C/D frag: col = lane&15, row = (lane>>4)*4 + reg
  const int u = hb + wc * 16 + l15;
  const float bi = biasc[u], bff = biasc[512 + u], bg = biasc[1024 + u], bo = biasc[1536 + u];
#pragma unroll
  for (int m = 0; m < 4; ++m) {
    const int rbase = rowBlk + wr * 64 + m * 16 + l4 * 4;
    const size_t cmi = (size_t)u * NSEQ + rbase;       // column-major index
    f32x4 co4 = *(const f32x4*)(c_state + cmi);
    int4 ln4 = *(const int4*)(lens + rbase);
    f32x4 ho4;
    if (hf_new) ho4 = *(const f32x4*)(hf_old + cmi);
    f32x4 cn4, hn4;
    u16 hstore[4];
#pragma unroll
    for (int jj = 0; jj < 4; ++jj) {
      const int r = rbase + jj;
      float ip = acc[m][0][jj] + bi;
      float fp = acc[m][1][jj] + bff;
      float gp = acc[m][2][jj] + bg;
      float op = acc[m][3][jj] + bo;
      float co = co4[jj];
      float si = 1.f / (1.f + __expf(-ip));
      float sf = 1.f / (1.f + __expf(-fp));
      float so = 1.f / (1.f + __expf(-op));
      float tg = tanhf(gp);
      float cn = sf * co + si * tg;
      float hn = so * tanhf(cn);
      int len = (jj == 0) ? ln4.x : (jj == 1) ? ln4.y : (jj == 2) ? ln4.z : ln4.w;
      bool act = t < len;
      cn4[jj] = act ? cn : co;
      hstore[jj] = act ? f2bf(hn) : segA1[(size_t)r * HID + u];
      if (hf_new) hn4[jj] = act ? hn : ho4[jj];
    }
    *(f32x4*)(c_state + cmi) = cn4;
    if (hf_new) *(f32x4*)(hf_new + cmi) = hn4;
#pragma unroll
    for (int jj = 0; jj < 4; ++jj)
      h_new[(size_t)(rbase + jj) * HID + u] = hstore[jj];
  }
}

// ---------- scores: out[n] = dot(h2[:,n] (col-major), enc[n/100,:]) ----------
__global__ __launch_bounds__(256) void scores_kernel(
    const float* __restrict__ h2cm, const float* __restrict__ enc, float* __restrict__ out) {
  int n = (blockIdx.x >> 1) * 256 + threadIdx.x;      // 25 n-blocks x 2 u-halves
  int uh = (blockIdx.x & 1) * 256;
  const float* ep = enc + (n / 100) * HID + uh;
  float s = 0.f;
#pragma unroll 8
  for (int u = 0; u < 256; ++u) s += h2cm[(size_t)(uh + u) * NSEQ + n] * ep[u];
  atomicAdd(&out[n], s);
}

// ---------- relevance dtype detection (bool may arrive as u8/i32/i64/f32) ----------
__global__ void detect_kernel(const unsigned char* __restrict__ rel, int* __restrict__ flags) {
  int a = 0, bb = 0, z = 0;
  for (int i = blockIdx.x * blockDim.x + threadIdx.x; i < RELN; i += gridDim.x * blockDim.x) {
    if (rel[i]) {
      if (i & 3) a = 1; else z = 1;
      if (i & 4) bb = 1;
    }
  }
  if (a) atomicOr(&flags[0], 1);
  if (bb) atomicOr(&flags[1], 1);
  if (z) atomicOr(&flags[2], 1);
}

__global__ void qt_kernel(const void* __restrict__ rel, const int* __restrict__ qt_idx,
                          const int* __restrict__ opt_idx, const int* __restrict__ flags,
                          float* __restrict__ out) {
  int n = blockIdx.x * blockDim.x + threadIdx.x;
  if (n >= NSEQ) return;
  long long idx = (long long)qt_idx[n / 100] * NANS + opt_idx[n];
  int fa = flags[0], fb = flags[1], fz = flags[2];
  bool hit;
  if (fa && fz)       hit = ((const unsigned char*)rel)[idx] != 0;   // uint8 bool
  else if (fa)        hit = ((const float*)rel)[idx] != 0.f;         // float32
  else if (fb)        hit = ((const int*)rel)[idx] != 0;             // int32
  else                hit = ((const long long*)rel)[idx] != 0;       // int64
  out[NSEQ + n] = hit ? 1.f : 0.f;
}

extern "C" void kernel_launch(void* const* d_in, const int* in_sizes, int n_in,
                              void* d_out, int out_size, void* d_ws, size_t ws_size,
                              hipStream_t stream) {
  (void)in_sizes; (void)n_in; (void)out_size; (void)ws_size;
  const float* enc    = (const float*)d_in[0];
  const int*   opt    = (const int*)d_in[1];
  const int*   optlen = (const int*)d_in[2];
  const int*   qtidx  = (const int*)d_in[3];
  const int*   optidx = (const int*)d_in[4];
  const float* Wemb   = (const float*)d_in[5];
  const float* wih0   = (const float*)d_in[6];
  const float* whh0   = (const float*)d_in[7];
  const float* bih0   = (const float*)d_in[8];
  const float* bhh0   = (const float*)d_in[9];
  const float* wih1   = (const float*)d_in[10];
  const float* whh1   = (const float*)d_in[11];
  const float* bih1   = (const float*)d_in[12];
  const float* bhh1   = (const float*)d_in[13];
  const void*  rel    = d_in[14];
  float* out = (float*)d_out;

  char* ws = (char*)d_ws;
  size_t off = 0;
  auto alloc = [&](size_t bytes) -> void* {
    void* p = (void*)(ws + off);
    off += (bytes + 255) & ~(size_t)255;
    return p;
  };
  u16* embT   = (u16*)alloc((size_t)TMAX * NSEQ * EMBP * 2);
  u16* W0     = (u16*)alloc((size_t)2048 * KL0 * 2);
  u16* W1     = (u16*)alloc((size_t)2048 * KL1 * 2);
  float* bc0  = (float*)alloc(2048 * 4);
  float* bc1  = (float*)alloc(2048 * 4);
  u16* h0b[2] = { (u16*)alloc((size_t)NSEQ * HID * 2), (u16*)alloc((size_t)NSEQ * HID * 2) };
  u16* h1b[2] = { (u16*)alloc((size_t)NSEQ * HID * 2), (u16*)alloc((size_t)NSEQ * HID * 2) };
  float* c0   = (float*)alloc((size_t)NSEQ * HID * 4);
  float* c1   = (float*)alloc((size_t)NSEQ * HID * 4);
  float* hf[2] = { (float*)alloc((size_t)NSEQ * HID * 4), (float*)alloc((size_t)NSEQ * HID * 4) };
  int* flags  = (int*)alloc(16);

  hipMemsetAsync(h0b[0], 0, (size_t)NSEQ * HID * 2, stream);
  hipMemsetAsync(h1b[0], 0, (size_t)NSEQ * HID * 2, stream);
  hipMemsetAsync(c0, 0, (size_t)NSEQ * HID * 4, stream);
  hipMemsetAsync(c1, 0, (size_t)NSEQ * HID * 4, stream);
  hipMemsetAsync(hf[0], 0, (size_t)NSEQ * HID * 4, stream);
  hipMemsetAsync(flags, 0, 16, stream);
  hipMemsetAsync(out, 0, (size_t)NSEQ * 4, stream);   // scores accumulated atomically

  embed_kernel<<<NSEQ, EMBP, 0, stream>>>(opt, Wemb, embT);
  prep_w0<<<512, 256, 0, stream>>>(wih0, whh0, W0);
  prep_w1<<<512, 256, 0, stream>>>(wih1, whh1, W1);
  prep_bias<<<8, 256, 0, stream>>>(bih0, bhh0, bc0);
  prep_bias<<<8, 256, 0, stream>>>(bih1, bhh1, bc1);
  detect_kernel<<<256, 256, 0, stream>>>((const unsigned char*)rel, flags);

  for (int t = 0; t < TMAX; ++t) {
    int cur = t & 1, nxt = cur ^ 1;
    // layer 0: A = [emb_t | h0], B = W0cat
    lstm_step<<<800, 256, 0, stream>>>(
        embT + (size_t)t * NSEQ * EMBP, EMBP, EMBP,
        h0b[cur], W0, KL0, KL0 / 32, bc0,
        h0b[nxt], c0, nullptr, nullptr, optlen, t);
    // layer 1: A = [h0_new | h1], B = W1cat
    lstm_step<<<800, 256, 0, stream>>>(
        h0b[nxt], HID, HID,
        h1b[cur], W1, KL1, KL1 / 32, bc1,
        h1b[nxt], c1, hf[cur], hf[nxt], optlen, t);
  }

  scores_kernel<<<50, 256, 0, stream>>>(hf[0], enc, out);
  qt_kernel<<<(NSEQ + 255) / 256, 256, 0, stream>>>(rel, qtidx, optidx, flags, out);
}